// Round 1
// baseline (5369.565 us; speedup 1.0000x reference)
//
#include <hip/hip_runtime.h>
#include <math.h>

#define BB 64
#define SS 128
#define DD 1024
#define HH 512
#define EE 512
#define VV 32000
#define NSTEP 31
#define G4 2048        // 4*H
#define XDIM 1536      // E + D_enc

// ---------------- workspace layout (in floats) ----------------
#define OFF_KEYS   0L                                  // 8388608
#define OFF_K2     8388608L                            // 4194304
#define OFF_SB     12582912L                           // 8192
#define OFF_MA     12591104L                           // 8192
#define OFF_STATE  12599296L                           // 131072 (h0,c0,h1,c1)
#define OFF_X      12730368L                           // 98304
#define OFF_P      12828672L                           // 2097152
#define OFF_PRED   14925824L                           // 64 (ints)
#define OFF_LOG    14925888L                           // 63488000
#define TOTAL_BUF  78413888L
#define TOTAL_FB   14925952L

// =====================================================================
// Generic GEMM: C[m,n] = sum_k A[m,k] * B(n,k or k,n) + bias[n]
// BT=1: B is (N,K) row-major (B-transposed / dot-product form)
// BT=0: B is (K,N) row-major
// BM=64, BN=128, BK=32, 256 threads, TM=4, TN=8.
// Requires M%64==0, N%128==0, K%32==0.
// C element index = coff + m*ldm + n*ldn  (supports strided scatter)
// =====================================================================
template<int BT>
__global__ __launch_bounds__(256)
void gemm_kernel(const float* __restrict__ A, const float* __restrict__ Bm,
                 const float* __restrict__ bias, float* __restrict__ C,
                 int M, int N, int K, long ldm, long ldn, long coff)
{
    __shared__ float As[32][68];
    __shared__ float Bs[32][132];
    int tid = threadIdx.x;
    int tx = tid & 15, ty = tid >> 4;
    int m0 = blockIdx.y * 64, n0 = blockIdx.x * 128;

    float acc[4][8];
#pragma unroll
    for (int i = 0; i < 4; ++i)
#pragma unroll
        for (int j = 0; j < 8; ++j) acc[i][j] = 0.0f;

    int ar = tid >> 3;          // 0..31
    int ac = (tid & 7) * 4;     // 0,4,...,28

    for (int kk = 0; kk < K; kk += 32) {
        // ---- load A tile (64 x 32), store transposed As[k][m]
#pragma unroll
        for (int p = 0; p < 2; ++p) {
            int r = ar + p * 32;
            float4 v = *(const float4*)(A + (long)(m0 + r) * K + kk + ac);
            As[ac + 0][r] = v.x; As[ac + 1][r] = v.y;
            As[ac + 2][r] = v.z; As[ac + 3][r] = v.w;
        }
        // ---- load B tile (128 x 32) as Bs[k][n]
        if (BT) {
#pragma unroll
            for (int p = 0; p < 4; ++p) {
                int n = ar + p * 32;
                float4 v = *(const float4*)(Bm + (long)(n0 + n) * K + kk + ac);
                Bs[ac + 0][n] = v.x; Bs[ac + 1][n] = v.y;
                Bs[ac + 2][n] = v.z; Bs[ac + 3][n] = v.w;
            }
        } else {
            int bn = (tid & 31) * 4;   // 0..124
            int bk = tid >> 5;         // 0..7
#pragma unroll
            for (int p = 0; p < 4; ++p) {
                int k = bk + p * 8;
                float4 v = *(const float4*)(Bm + (long)(kk + k) * N + n0 + bn);
                *(float4*)&Bs[k][bn] = v;
            }
        }
        __syncthreads();
#pragma unroll
        for (int k = 0; k < 32; ++k) {
            float4 a  = *(const float4*)&As[k][ty * 4];
            float4 b0 = *(const float4*)&Bs[k][tx * 8];
            float4 b1 = *(const float4*)&Bs[k][tx * 8 + 4];
            float av[4] = {a.x, a.y, a.z, a.w};
            float bv[8] = {b0.x, b0.y, b0.z, b0.w, b1.x, b1.y, b1.z, b1.w};
#pragma unroll
            for (int im = 0; im < 4; ++im)
#pragma unroll
                for (int in = 0; in < 8; ++in)
                    acc[im][in] = fmaf(av[im], bv[in], acc[im][in]);
        }
        __syncthreads();
    }

#pragma unroll
    for (int im = 0; im < 4; ++im) {
        int m = m0 + ty * 4 + im;
#pragma unroll
        for (int in = 0; in < 8; ++in) {
            int n = n0 + tx * 8 + in;
            float r = acc[im][in];
            if (bias) r += bias[n];
            C[coff + (long)m * ldm + (long)n * ldn] = r;
        }
    }
}

// =====================================================================
// LSTM gates split-K GEMM: partial[z] = A_z_chunk @ B_z_chunk^T
// z < z1 -> chunk z of A1(64,K1) x B1(2048,K1); else chunk of A2 x B2.
// Kc = 128. Grid: (2048/128, z1+z2). Output P[z][64][2048].
// =====================================================================
__global__ __launch_bounds__(256)
void lstm_gates(const float* __restrict__ A1, int K1, const float* __restrict__ B1,
                const float* __restrict__ A2, int K2c, const float* __restrict__ B2,
                int z1, float* __restrict__ P)
{
    __shared__ float As[32][68];
    __shared__ float Bs[32][132];
    int tid = threadIdx.x;
    int tx = tid & 15, ty = tid >> 4;
    int n0 = blockIdx.x * 128;
    int z = blockIdx.y;

    const float* A; const float* Bw; int kb, lda;
    if (z < z1) { A = A1; Bw = B1; kb = z * 128;        lda = K1; }
    else        { A = A2; Bw = B2; kb = (z - z1) * 128; lda = K2c; }

    float acc[4][8];
#pragma unroll
    for (int i = 0; i < 4; ++i)
#pragma unroll
        for (int j = 0; j < 8; ++j) acc[i][j] = 0.0f;

    int ar = tid >> 3;
    int ac = (tid & 7) * 4;

    for (int kk = kb; kk < kb + 128; kk += 32) {
#pragma unroll
        for (int p = 0; p < 2; ++p) {
            int r = ar + p * 32;
            float4 v = *(const float4*)(A + (long)r * lda + kk + ac);
            As[ac + 0][r] = v.x; As[ac + 1][r] = v.y;
            As[ac + 2][r] = v.z; As[ac + 3][r] = v.w;
        }
#pragma unroll
        for (int p = 0; p < 4; ++p) {
            int n = ar + p * 32;
            float4 v = *(const float4*)(Bw + (long)(n0 + n) * lda + kk + ac);
            Bs[ac + 0][n] = v.x; Bs[ac + 1][n] = v.y;
            Bs[ac + 2][n] = v.z; Bs[ac + 3][n] = v.w;
        }
        __syncthreads();
#pragma unroll
        for (int k = 0; k < 32; ++k) {
            float4 a  = *(const float4*)&As[k][ty * 4];
            float4 b0 = *(const float4*)&Bs[k][tx * 8];
            float4 b1 = *(const float4*)&Bs[k][tx * 8 + 4];
            float av[4] = {a.x, a.y, a.z, a.w};
            float bv[8] = {b0.x, b0.y, b0.z, b0.w, b1.x, b1.y, b1.z, b1.w};
#pragma unroll
            for (int im = 0; im < 4; ++im)
#pragma unroll
                for (int in = 0; in < 8; ++in)
                    acc[im][in] = fmaf(av[im], bv[in], acc[im][in]);
        }
        __syncthreads();
    }

    float* Pp = P + (long)z * (BB * (long)G4);
#pragma unroll
    for (int im = 0; im < 4; ++im) {
        int m = ty * 4 + im;
#pragma unroll
        for (int in = 0; in < 8; ++in)
            Pp[(long)m * G4 + n0 + tx * 8 + in] = acc[im][in];
    }
}

// ---- sum split-K partials, add biases, apply LSTM cell ----
__global__ __launch_bounds__(256)
void lstm_act(const float* __restrict__ P, int z,
              const float* __restrict__ b_ih, const float* __restrict__ b_hh,
              float* __restrict__ c, float* __restrict__ h)
{
    int idx = blockIdx.x * 256 + threadIdx.x;   // 0..32767
    int b = idx >> 9, j = idx & 511;
    float gi = 0, gf = 0, gg = 0, go = 0;
    for (int zi = 0; zi < z; ++zi) {
        const float* p = P + (long)zi * (BB * (long)G4) + (long)b * G4 + j;
        gi += p[0]; gf += p[HH]; gg += p[2 * HH]; go += p[3 * HH];
    }
    gi += b_ih[j] + b_hh[j];
    gf += b_ih[HH + j] + b_hh[HH + j];
    gg += b_ih[2 * HH + j] + b_hh[2 * HH + j];
    go += b_ih[3 * HH + j] + b_hh[3 * HH + j];
    float i_ = 1.0f / (1.0f + expf(-gi));
    float f_ = 1.0f / (1.0f + expf(-gf));
    float g_ = tanhf(gg);
    float o_ = 1.0f / (1.0f + expf(-go));
    float cn = f_ * c[idx] + i_ * g_;
    c[idx] = cn;
    h[idx] = o_ * tanhf(cn);
}

// ---- fused: embedding gather + attention (scores/softmax/ctx) -> x ----
__global__ __launch_bounds__(256)
void attn_embed(const float* __restrict__ h1, const float* __restrict__ K2,
                const float* __restrict__ sb, const float* __restrict__ mA,
                const float* __restrict__ enc, const float* __restrict__ emb,
                const int* __restrict__ pred, float* __restrict__ x)
{
    __shared__ float shH[512];
    __shared__ float shP[256];
    __shared__ float shS[128];
    __shared__ float shR[64];
    int b = blockIdx.x, tid = threadIdx.x;

    shH[tid]       = h1[b * HH + tid];
    shH[tid + 256] = h1[b * HH + 256 + tid];
    const float* et = emb + (long)pred[b] * EE;
    float* xr = x + (long)b * XDIM;
    xr[tid]       = et[tid];
    xr[tid + 256] = et[tid + 256];
    __syncthreads();

    {   // scores: 2 threads per source position
        int s = tid >> 1, hf = tid & 1;
        const float* kp = K2 + ((long)(b * SS + s)) * HH + hf * 256;
        const float* hp = shH + hf * 256;
        float a = 0;
        for (int j = 0; j < 256; j += 4) {
            float4 v = *(const float4*)(kp + j);
            a += hp[j] * v.x + hp[j + 1] * v.y + hp[j + 2] * v.z + hp[j + 3] * v.w;
        }
        shP[tid] = a;
    }
    __syncthreads();
    if (tid < 128) {
        float sc = (shP[2 * tid] + shP[2 * tid + 1] + sb[b * SS + tid]) * 0.03125f
                   + mA[b * SS + tid];
        shS[tid] = sc;
    }
    __syncthreads();
    // max reduce (128)
    if (tid < 64) shR[tid] = fmaxf(shS[tid], shS[tid + 64]);
    __syncthreads();
    if (tid < 32) shR[tid] = fmaxf(shR[tid], shR[tid + 32]);
    __syncthreads();
    if (tid < 16) shR[tid] = fmaxf(shR[tid], shR[tid + 16]);
    __syncthreads();
    if (tid < 8)  shR[tid] = fmaxf(shR[tid], shR[tid + 8]);
    __syncthreads();
    if (tid < 4)  shR[tid] = fmaxf(shR[tid], shR[tid + 4]);
    __syncthreads();
    if (tid < 2)  shR[tid] = fmaxf(shR[tid], shR[tid + 2]);
    __syncthreads();
    if (tid == 0) shR[0] = fmaxf(shR[0], shR[1]);
    __syncthreads();
    float mx = shR[0];
    __syncthreads();
    if (tid < 128) shS[tid] = expf(shS[tid] - mx);
    __syncthreads();
    // sum reduce
    if (tid < 64) shR[tid] = shS[tid] + shS[tid + 64];
    __syncthreads();
    if (tid < 32) shR[tid] += shR[tid + 32];
    __syncthreads();
    if (tid < 16) shR[tid] += shR[tid + 16];
    __syncthreads();
    if (tid < 8)  shR[tid] += shR[tid + 8];
    __syncthreads();
    if (tid < 4)  shR[tid] += shR[tid + 4];
    __syncthreads();
    if (tid < 2)  shR[tid] += shR[tid + 2];
    __syncthreads();
    if (tid == 0) shR[0] += shR[1];
    __syncthreads();
    float inv = 1.0f / shR[0];
    if (tid < 128) shS[tid] *= inv;
    __syncthreads();
    // ctx: each thread owns 4 contiguous d
    const float* ep = enc + (long)b * SS * DD + tid * 4;
    float4 a4 = {0, 0, 0, 0};
    for (int s = 0; s < SS; ++s) {
        float a = shS[s];
        float4 v = *(const float4*)(ep + (long)s * DD);
        a4.x += a * v.x; a4.y += a * v.y; a4.z += a * v.z; a4.w += a * v.w;
    }
    *(float4*)(xr + EE + tid * 4) = a4;
}

// ---- greedy argmax matching jnp.argmax (first max) ----
__global__ __launch_bounds__(256)
void argmax_kernel(const float* __restrict__ L, long rowStride, long vStride,
                   int* __restrict__ pred)
{
    __shared__ float shV[256];
    __shared__ int   shI[256];
    int b = blockIdx.x, tid = threadIdx.x;
    const float* p = L + (long)b * rowStride;
    float best = -INFINITY; int bi = 0;
    for (int v = tid; v < VV; v += 256) {
        float val = p[(long)v * vStride];
        if (val > best) { best = val; bi = v; }
    }
    shV[tid] = best; shI[tid] = bi;
    __syncthreads();
    for (int o = 128; o > 0; o >>= 1) {
        if (tid < o) {
            float ov = shV[tid + o]; int oi = shI[tid + o];
            if (ov > shV[tid] || (ov == shV[tid] && oi < shI[tid])) {
                shV[tid] = ov; shI[tid] = oi;
            }
        }
        __syncthreads();
    }
    if (tid == 0) pred[b] = shI[0];
}

// ---- (T,B,V) -> (B,V,T) transpose via LDS, coalesced both sides ----
__global__ __launch_bounds__(256)
void transpose_out(const float* __restrict__ Lall, float* __restrict__ out)
{
    __shared__ float tile[NSTEP][129];
    int b = blockIdx.x, v0 = blockIdx.y * 128, tid = threadIdx.x;
    int i = tid & 127, th = tid >> 7;
    for (int tp = 0; tp < 16; ++tp) {
        int t = th + tp * 2;
        if (t < NSTEP)
            tile[t][i] = Lall[(long)t * BB * VV + (long)b * VV + v0 + i];
    }
    __syncthreads();
    long obase = (long)b * VV * NSTEP + (long)v0 * NSTEP;
    for (int w = tid; w < 128 * NSTEP; w += 256)
        out[obase + w] = tile[w % NSTEP][w / NSTEP];
}

// ---- detect mask dtype (uint8 vs int32/other) and canonicalize ----
__global__ void mask_canon(const void* __restrict__ maskp, float* __restrict__ mA)
{
    __shared__ int ok;
    const unsigned char* bt = (const unsigned char*)maskp;
    int tid = threadIdx.x;
    if (tid == 0) ok = 1;
    __syncthreads();
    int bad = 0;
    for (int i = tid; i < BB * SS; i += 256) {
        unsigned char v = bt[i];
        if (v > 1) bad = 1;                                    // not a {0,1} byte stream
        if ((i & (SS - 1)) != 0 && bt[i - 1] > v) bad = 1;     // descent within row: impossible for real bool mask
    }
    if (bad) atomicAnd(&ok, 0);
    __syncthreads();
    int packed = ok;
    const int* wi = (const int*)maskp;
    for (int i = tid; i < BB * SS; i += 256) {
        int m = packed ? (bt[i] != 0) : (wi[i] != 0);
        mA[i] = m ? -1.0e10f : 0.0f;
    }
}

// ---- zero h/c state, set pred = START ----
__global__ void init_state(float* __restrict__ st, int* __restrict__ pred)
{
    int idx = blockIdx.x * 256 + threadIdx.x;   // grid 512 -> 131072
    st[idx] = 0.0f;
    if (idx < BB) pred[idx] = 1;
}

// ---- sb[bs] = dot(bq, keys[bs]) ----
__global__ void sb_kernel(const float* __restrict__ keys, const float* __restrict__ bq,
                          float* __restrict__ sb)
{
    int bs = blockIdx.x * 256 + threadIdx.x;    // grid 32 -> 8192
    const float* kp = keys + (long)bs * DD;
    float a = 0;
    for (int d = 0; d < DD; d += 4) {
        float4 kv = *(const float4*)(kp + d);
        float4 bv = *(const float4*)(bq + d);
        a += kv.x * bv.x + kv.y * bv.y + kv.z * bv.z + kv.w * bv.w;
    }
    sb[bs] = a;
}

extern "C" void kernel_launch(void* const* d_in, const int* in_sizes, int n_in,
                              void* d_out, int out_size, void* d_ws, size_t ws_size,
                              hipStream_t stream)
{
    const float* enc   = (const float*)d_in[0];
    const void*  maskp = d_in[1];
    const float* embt  = (const float*)d_in[2];
    const float* wq    = (const float*)d_in[3];
    const float* bq    = (const float*)d_in[4];
    const float* wk    = (const float*)d_in[5];
    const float* bk    = (const float*)d_in[6];
    const float* w_ih0 = (const float*)d_in[7];
    const float* w_hh0 = (const float*)d_in[8];
    const float* b_ih0 = (const float*)d_in[9];
    const float* b_hh0 = (const float*)d_in[10];
    const float* w_ih1 = (const float*)d_in[11];
    const float* w_hh1 = (const float*)d_in[12];
    const float* b_ih1 = (const float*)d_in[13];
    const float* b_hh1 = (const float*)d_in[14];
    const float* w_out = (const float*)d_in[15];
    const float* b_out = (const float*)d_in[16];

    float* out  = (float*)d_out;
    float* w    = (float*)d_ws;
    float* keys = w + OFF_KEYS;
    float* K2b  = w + OFF_K2;
    float* sbb  = w + OFF_SB;
    float* mA   = w + OFF_MA;
    float* h0   = w + OFF_STATE;
    float* c0   = h0 + BB * HH;
    float* h1   = c0 + BB * HH;
    float* c1   = h1 + BB * HH;
    float* xb   = w + OFF_X;
    float* P    = w + OFF_P;
    int*   pred = (int*)(w + OFF_PRED);
    float* wlog = w + OFF_LOG;

    bool buffered = ws_size >= (size_t)TOTAL_BUF * 4;

    mask_canon<<<1, 256, 0, stream>>>(maskp, mA);
    init_state<<<512, 256, 0, stream>>>(w + OFF_STATE, pred);

    // keys = enc @ wk^T + bk      (8192 x 1024, K=1024)
    gemm_kernel<1><<<dim3(8, 128), 256, 0, stream>>>(
        enc, wk, bk, keys, BB * SS, DD, DD, (long)DD, 1L, 0L);
    // K2 = keys @ wq              (8192 x 512, K=1024), B is (K,N)
    gemm_kernel<0><<<dim3(4, 128), 256, 0, stream>>>(
        keys, wq, nullptr, K2b, BB * SS, HH, DD, (long)HH, 1L, 0L);
    // sb = keys . bq
    sb_kernel<<<32, 256, 0, stream>>>(keys, bq, sbb);

    for (int t = 0; t < NSTEP; ++t) {
        attn_embed<<<BB, 256, 0, stream>>>(h1, K2b, sbb, mA, enc, embt, pred, xb);
        // layer 0: gates = x@w_ih0^T + h0@w_hh0^T   (split-K partials)
        lstm_gates<<<dim3(16, 16), 256, 0, stream>>>(xb, XDIM, w_ih0, h0, HH, w_hh0, 12, P);
        lstm_act<<<128, 256, 0, stream>>>(P, 16, b_ih0, b_hh0, c0, h0);
        // layer 1: gates = h0@w_ih1^T + h1@w_hh1^T
        lstm_gates<<<dim3(16, 8), 256, 0, stream>>>(h0, HH, w_ih1, h1, HH, w_hh1, 4, P);
        lstm_act<<<128, 256, 0, stream>>>(P, 8, b_ih1, b_hh1, c1, h1);

        if (buffered) {
            float* Lt = wlog + (long)t * BB * VV;
            gemm_kernel<1><<<dim3(250, 1), 256, 0, stream>>>(
                h1, w_out, b_out, Lt, BB, VV, HH, (long)VV, 1L, 0L);
            argmax_kernel<<<BB, 256, 0, stream>>>(Lt, (long)VV, 1L, pred);
        } else {
            // scatter logits straight into (B,V,T) output
            gemm_kernel<1><<<dim3(250, 1), 256, 0, stream>>>(
                h1, w_out, b_out, out, BB, VV, HH, (long)VV * NSTEP, (long)NSTEP, (long)t);
            argmax_kernel<<<BB, 256, 0, stream>>>(out + t, (long)VV * NSTEP, (long)NSTEP, pred);
        }
    }
    if (buffered)
        transpose_out<<<dim3(BB, VV / 128), 256, 0, stream>>>(wlog, out);
}

// Round 2
// 4696.707 us; speedup vs baseline: 1.1433x; 1.1433x over previous
//
#include <hip/hip_runtime.h>
#include <math.h>

#define BB 64
#define SS 128
#define DD 1024
#define HH 512
#define EE 512
#define VV 32000
#define NSTEP 31
#define G4 2048        // 4*H
#define XDIM 1536      // E + D_enc

// ---------------- workspace layout (in floats) ----------------
#define OFF_KEYS   0L                                  // 8388608
#define OFF_K2     8388608L                            // 4194304
#define OFF_SB     12582912L                           // 8192
#define OFF_MA     12591104L                           // 8192
#define OFF_STATE  12599296L                           // 131072 (h0,c0,h1,c1)
#define OFF_X      12730368L                           // 98304
#define OFF_P      12828672L                           // 2097152
#define OFF_PRED   14925824L                           // 64 (ints)
#define OFF_WH     14925888L                           // 8192000 (16.384M bf16)
#define OFF_WL     23117888L                           // 8192000
#define OFF_H1H    31309888L                           // 16384 (32768 bf16)
#define OFF_H1L    31326272L                           // 16384
#define OFF_LOG    31342656L                           // 63488000
#define TOTAL_BUF  94830656L
#define TOTAL_FB   31342656L

typedef __attribute__((ext_vector_type(8))) short short8;
typedef __attribute__((ext_vector_type(4))) float float4v;

__device__ __forceinline__ unsigned short bf16_rne(float v)
{
    unsigned u = __float_as_uint(v);
    unsigned r = (u + 0x7FFF + ((u >> 16) & 1)) >> 16;
    return (unsigned short)r;
}

// =====================================================================
// Generic fp32 GEMM (kept for keys/K2 and as logits fallback)
// =====================================================================
template<int BT>
__global__ __launch_bounds__(256)
void gemm_kernel(const float* __restrict__ A, const float* __restrict__ Bm,
                 const float* __restrict__ bias, float* __restrict__ C,
                 int M, int N, int K, long ldm, long ldn, long coff)
{
    __shared__ float As[32][68];
    __shared__ float Bs[32][132];
    int tid = threadIdx.x;
    int tx = tid & 15, ty = tid >> 4;
    int m0 = blockIdx.y * 64, n0 = blockIdx.x * 128;

    float acc[4][8];
#pragma unroll
    for (int i = 0; i < 4; ++i)
#pragma unroll
        for (int j = 0; j < 8; ++j) acc[i][j] = 0.0f;

    int ar = tid >> 3;          // 0..31
    int ac = (tid & 7) * 4;     // 0,4,...,28

    for (int kk = 0; kk < K; kk += 32) {
#pragma unroll
        for (int p = 0; p < 2; ++p) {
            int r = ar + p * 32;
            float4 v = *(const float4*)(A + (long)(m0 + r) * K + kk + ac);
            As[ac + 0][r] = v.x; As[ac + 1][r] = v.y;
            As[ac + 2][r] = v.z; As[ac + 3][r] = v.w;
        }
        if (BT) {
#pragma unroll
            for (int p = 0; p < 4; ++p) {
                int n = ar + p * 32;
                float4 v = *(const float4*)(Bm + (long)(n0 + n) * K + kk + ac);
                Bs[ac + 0][n] = v.x; Bs[ac + 1][n] = v.y;
                Bs[ac + 2][n] = v.z; Bs[ac + 3][n] = v.w;
            }
        } else {
            int bn = (tid & 31) * 4;
            int bk = tid >> 5;
#pragma unroll
            for (int p = 0; p < 4; ++p) {
                int k = bk + p * 8;
                float4 v = *(const float4*)(Bm + (long)(kk + k) * N + n0 + bn);
                *(float4*)&Bs[k][bn] = v;
            }
        }
        __syncthreads();
#pragma unroll
        for (int k = 0; k < 32; ++k) {
            float4 a  = *(const float4*)&As[k][ty * 4];
            float4 b0 = *(const float4*)&Bs[k][tx * 8];
            float4 b1 = *(const float4*)&Bs[k][tx * 8 + 4];
            float av[4] = {a.x, a.y, a.z, a.w};
            float bv[8] = {b0.x, b0.y, b0.z, b0.w, b1.x, b1.y, b1.z, b1.w};
#pragma unroll
            for (int im = 0; im < 4; ++im)
#pragma unroll
                for (int in = 0; in < 8; ++in)
                    acc[im][in] = fmaf(av[im], bv[in], acc[im][in]);
        }
        __syncthreads();
    }

#pragma unroll
    for (int im = 0; im < 4; ++im) {
        int m = m0 + ty * 4 + im;
#pragma unroll
        for (int in = 0; in < 8; ++in) {
            int n = n0 + tx * 8 + in;
            float r = acc[im][in];
            if (bias) r += bias[n];
            C[coff + (long)m * ldm + (long)n * ldn] = r;
        }
    }
}

// =====================================================================
// bf16 hi/lo split of an fp32 array (RNE both halves)
// =====================================================================
__global__ __launch_bounds__(256)
void split_kernel(const float* __restrict__ x, unsigned short* __restrict__ hi,
                  unsigned short* __restrict__ lo, int n)
{
    int i = (blockIdx.x * 256 + threadIdx.x) * 4;
    if (i >= n) return;
    float4 v = *(const float4*)(x + i);
    float vv[4] = {v.x, v.y, v.z, v.w};
    unsigned hpack[2], lpack[2];
#pragma unroll
    for (int p = 0; p < 2; ++p) {
        unsigned short h0 = bf16_rne(vv[2 * p]);
        unsigned short h1 = bf16_rne(vv[2 * p + 1]);
        float f0 = __uint_as_float((unsigned)h0 << 16);
        float f1 = __uint_as_float((unsigned)h1 << 16);
        unsigned short l0 = bf16_rne(vv[2 * p] - f0);
        unsigned short l1 = bf16_rne(vv[2 * p + 1] - f1);
        hpack[p] = (unsigned)h0 | ((unsigned)h1 << 16);
        lpack[p] = (unsigned)l0 | ((unsigned)l1 << 16);
    }
    *(uint2*)(hi + i) = make_uint2(hpack[0], hpack[1]);
    *(uint2*)(lo + i) = make_uint2(lpack[0], lpack[1]);
}

// =====================================================================
// Logits GEMM via bf16-split MFMA: C(64,32000) = h1(64,512) @ w_out^T
// No LDS, no barriers. Wave owns n-tile of 32 (2 n-frags), all 64 m rows.
// Grid: 32000/(4 waves * 32) = 250 blocks x 256 threads.
// =====================================================================
__global__ __launch_bounds__(256)
void logits_mfma(const unsigned short* __restrict__ Ah, const unsigned short* __restrict__ Al,
                 const unsigned short* __restrict__ Bh, const unsigned short* __restrict__ Bl,
                 const float* __restrict__ bias, float* __restrict__ C,
                 long ldm, long ldn, long coff)
{
    int tid = threadIdx.x;
    int wid = tid >> 6, lane = tid & 63;
    int ln = lane & 15, q = lane >> 4;
    int nb = blockIdx.x * 128 + wid * 32;      // wave n base (2 frags of 16)

    float4v acc[4][2];
#pragma unroll
    for (int mf = 0; mf < 4; ++mf)
#pragma unroll
        for (int nf = 0; nf < 2; ++nf)
            acc[mf][nf] = (float4v){0.f, 0.f, 0.f, 0.f};

    const int kb = q * 8;
#pragma unroll 2
    for (int k0 = 0; k0 < 512; k0 += 32) {
        long ko = k0 + kb;
        short8 a_h[4], a_l[4], b_h[2], b_l[2];
#pragma unroll
        for (int nf = 0; nf < 2; ++nf) {
            long row = (long)(nb + nf * 16 + ln) * 512 + ko;
            b_h[nf] = *(const short8*)(Bh + row);
            b_l[nf] = *(const short8*)(Bl + row);
        }
#pragma unroll
        for (int mf = 0; mf < 4; ++mf) {
            long row = (long)(mf * 16 + ln) * 512 + ko;
            a_h[mf] = *(const short8*)(Ah + row);
            a_l[mf] = *(const short8*)(Al + row);
        }
#pragma unroll
        for (int mf = 0; mf < 4; ++mf)
#pragma unroll
            for (int nf = 0; nf < 2; ++nf) {
                acc[mf][nf] = __builtin_amdgcn_mfma_f32_16x16x32_bf16(a_h[mf], b_h[nf], acc[mf][nf], 0, 0, 0);
                acc[mf][nf] = __builtin_amdgcn_mfma_f32_16x16x32_bf16(a_l[mf], b_h[nf], acc[mf][nf], 0, 0, 0);
                acc[mf][nf] = __builtin_amdgcn_mfma_f32_16x16x32_bf16(a_h[mf], b_l[nf], acc[mf][nf], 0, 0, 0);
            }
    }

#pragma unroll
    for (int nf = 0; nf < 2; ++nf) {
        int n = nb + nf * 16 + ln;
        float bo = bias[n];
#pragma unroll
        for (int mf = 0; mf < 4; ++mf)
#pragma unroll
            for (int r = 0; r < 4; ++r) {
                int m = mf * 16 + q * 4 + r;
                C[coff + (long)m * ldm + (long)n * ldn] = acc[mf][nf][r] + bo;
            }
    }
}

// =====================================================================
// LSTM gates split-K GEMM (unchanged)
// =====================================================================
__global__ __launch_bounds__(256)
void lstm_gates(const float* __restrict__ A1, int K1, const float* __restrict__ B1,
                const float* __restrict__ A2, int K2c, const float* __restrict__ B2,
                int z1, float* __restrict__ P)
{
    __shared__ float As[32][68];
    __shared__ float Bs[32][132];
    int tid = threadIdx.x;
    int tx = tid & 15, ty = tid >> 4;
    int n0 = blockIdx.x * 128;
    int z = blockIdx.y;

    const float* A; const float* Bw; int kb, lda;
    if (z < z1) { A = A1; Bw = B1; kb = z * 128;        lda = K1; }
    else        { A = A2; Bw = B2; kb = (z - z1) * 128; lda = K2c; }

    float acc[4][8];
#pragma unroll
    for (int i = 0; i < 4; ++i)
#pragma unroll
        for (int j = 0; j < 8; ++j) acc[i][j] = 0.0f;

    int ar = tid >> 3;
    int ac = (tid & 7) * 4;

    for (int kk = kb; kk < kb + 128; kk += 32) {
#pragma unroll
        for (int p = 0; p < 2; ++p) {
            int r = ar + p * 32;
            float4 v = *(const float4*)(A + (long)r * lda + kk + ac);
            As[ac + 0][r] = v.x; As[ac + 1][r] = v.y;
            As[ac + 2][r] = v.z; As[ac + 3][r] = v.w;
        }
#pragma unroll
        for (int p = 0; p < 4; ++p) {
            int n = ar + p * 32;
            float4 v = *(const float4*)(Bw + (long)(n0 + n) * lda + kk + ac);
            Bs[ac + 0][n] = v.x; Bs[ac + 1][n] = v.y;
            Bs[ac + 2][n] = v.z; Bs[ac + 3][n] = v.w;
        }
        __syncthreads();
#pragma unroll
        for (int k = 0; k < 32; ++k) {
            float4 a  = *(const float4*)&As[k][ty * 4];
            float4 b0 = *(const float4*)&Bs[k][tx * 8];
            float4 b1 = *(const float4*)&Bs[k][tx * 8 + 4];
            float av[4] = {a.x, a.y, a.z, a.w};
            float bv[8] = {b0.x, b0.y, b0.z, b0.w, b1.x, b1.y, b1.z, b1.w};
#pragma unroll
            for (int im = 0; im < 4; ++im)
#pragma unroll
                for (int in = 0; in < 8; ++in)
                    acc[im][in] = fmaf(av[im], bv[in], acc[im][in]);
        }
        __syncthreads();
    }

    float* Pp = P + (long)z * (BB * (long)G4);
#pragma unroll
    for (int im = 0; im < 4; ++im) {
        int m = ty * 4 + im;
#pragma unroll
        for (int in = 0; in < 8; ++in)
            Pp[(long)m * G4 + n0 + tx * 8 + in] = acc[im][in];
    }
}

// ---- sum split-K partials, biases, LSTM cell; optional bf16 split of h ----
__global__ __launch_bounds__(256)
void lstm_act(const float* __restrict__ P, int z,
              const float* __restrict__ b_ih, const float* __restrict__ b_hh,
              float* __restrict__ c, float* __restrict__ h,
              unsigned short* __restrict__ hh, unsigned short* __restrict__ hl)
{
    int idx = blockIdx.x * 256 + threadIdx.x;   // 0..32767
    int b = idx >> 9, j = idx & 511;
    float gi = 0, gf = 0, gg = 0, go = 0;
    for (int zi = 0; zi < z; ++zi) {
        const float* p = P + (long)zi * (BB * (long)G4) + (long)b * G4 + j;
        gi += p[0]; gf += p[HH]; gg += p[2 * HH]; go += p[3 * HH];
    }
    gi += b_ih[j] + b_hh[j];
    gf += b_ih[HH + j] + b_hh[HH + j];
    gg += b_ih[2 * HH + j] + b_hh[2 * HH + j];
    go += b_ih[3 * HH + j] + b_hh[3 * HH + j];
    float i_ = 1.0f / (1.0f + expf(-gi));
    float f_ = 1.0f / (1.0f + expf(-gf));
    float g_ = tanhf(gg);
    float o_ = 1.0f / (1.0f + expf(-go));
    float cn = f_ * c[idx] + i_ * g_;
    c[idx] = cn;
    float hv = o_ * tanhf(cn);
    h[idx] = hv;
    if (hh) {
        unsigned short hb = bf16_rne(hv);
        float hf = __uint_as_float((unsigned)hb << 16);
        hh[idx] = hb;
        hl[idx] = bf16_rne(hv - hf);
    }
}

// ---- fused: embedding gather + attention (unchanged) ----
__global__ __launch_bounds__(256)
void attn_embed(const float* __restrict__ h1, const float* __restrict__ K2,
                const float* __restrict__ sb, const float* __restrict__ mA,
                const float* __restrict__ enc, const float* __restrict__ emb,
                const int* __restrict__ pred, float* __restrict__ x)
{
    __shared__ float shH[512];
    __shared__ float shP[256];
    __shared__ float shS[128];
    __shared__ float shR[64];
    int b = blockIdx.x, tid = threadIdx.x;

    shH[tid]       = h1[b * HH + tid];
    shH[tid + 256] = h1[b * HH + 256 + tid];
    const float* et = emb + (long)pred[b] * EE;
    float* xr = x + (long)b * XDIM;
    xr[tid]       = et[tid];
    xr[tid + 256] = et[tid + 256];
    __syncthreads();

    {
        int s = tid >> 1, hf = tid & 1;
        const float* kp = K2 + ((long)(b * SS + s)) * HH + hf * 256;
        const float* hp = shH + hf * 256;
        float a = 0;
        for (int j = 0; j < 256; j += 4) {
            float4 v = *(const float4*)(kp + j);
            a += hp[j] * v.x + hp[j + 1] * v.y + hp[j + 2] * v.z + hp[j + 3] * v.w;
        }
        shP[tid] = a;
    }
    __syncthreads();
    if (tid < 128) {
        float sc = (shP[2 * tid] + shP[2 * tid + 1] + sb[b * SS + tid]) * 0.03125f
                   + mA[b * SS + tid];
        shS[tid] = sc;
    }
    __syncthreads();
    if (tid < 64) shR[tid] = fmaxf(shS[tid], shS[tid + 64]);
    __syncthreads();
    if (tid < 32) shR[tid] = fmaxf(shR[tid], shR[tid + 32]);
    __syncthreads();
    if (tid < 16) shR[tid] = fmaxf(shR[tid], shR[tid + 16]);
    __syncthreads();
    if (tid < 8)  shR[tid] = fmaxf(shR[tid], shR[tid + 8]);
    __syncthreads();
    if (tid < 4)  shR[tid] = fmaxf(shR[tid], shR[tid + 4]);
    __syncthreads();
    if (tid < 2)  shR[tid] = fmaxf(shR[tid], shR[tid + 2]);
    __syncthreads();
    if (tid == 0) shR[0] = fmaxf(shR[0], shR[1]);
    __syncthreads();
    float mx = shR[0];
    __syncthreads();
    if (tid < 128) shS[tid] = expf(shS[tid] - mx);
    __syncthreads();
    if (tid < 64) shR[tid] = shS[tid] + shS[tid + 64];
    __syncthreads();
    if (tid < 32) shR[tid] += shR[tid + 32];
    __syncthreads();
    if (tid < 16) shR[tid] += shR[tid + 16];
    __syncthreads();
    if (tid < 8)  shR[tid] += shR[tid + 8];
    __syncthreads();
    if (tid < 4)  shR[tid] += shR[tid + 4];
    __syncthreads();
    if (tid < 2)  shR[tid] += shR[tid + 2];
    __syncthreads();
    if (tid == 0) shR[0] += shR[1];
    __syncthreads();
    float inv = 1.0f / shR[0];
    if (tid < 128) shS[tid] *= inv;
    __syncthreads();
    const float* ep = enc + (long)b * SS * DD + tid * 4;
    float4 a4 = {0, 0, 0, 0};
    for (int s = 0; s < SS; ++s) {
        float a = shS[s];
        float4 v = *(const float4*)(ep + (long)s * DD);
        a4.x += a * v.x; a4.y += a * v.y; a4.z += a * v.z; a4.w += a * v.w;
    }
    *(float4*)(xr + EE + tid * 4) = a4;
}

// ---- greedy argmax matching jnp.argmax (first max) ----
__global__ __launch_bounds__(256)
void argmax_kernel(const float* __restrict__ L, long rowStride, long vStride,
                   int* __restrict__ pred)
{
    __shared__ float shV[256];
    __shared__ int   shI[256];
    int b = blockIdx.x, tid = threadIdx.x;
    const float* p = L + (long)b * rowStride;
    float best = -INFINITY; int bi = 0;
    for (int v = tid; v < VV; v += 256) {
        float val = p[(long)v * vStride];
        if (val > best) { best = val; bi = v; }
    }
    shV[tid] = best; shI[tid] = bi;
    __syncthreads();
    for (int o = 128; o > 0; o >>= 1) {
        if (tid < o) {
            float ov = shV[tid + o]; int oi = shI[tid + o];
            if (ov > shV[tid] || (ov == shV[tid] && oi < shI[tid])) {
                shV[tid] = ov; shI[tid] = oi;
            }
        }
        __syncthreads();
    }
    if (tid == 0) pred[b] = shI[0];
}

// ---- (T,B,V) -> (B,V,T) transpose via LDS ----
__global__ __launch_bounds__(256)
void transpose_out(const float* __restrict__ Lall, float* __restrict__ out)
{
    __shared__ float tile[NSTEP][129];
    int b = blockIdx.x, v0 = blockIdx.y * 128, tid = threadIdx.x;
    int i = tid & 127, th = tid >> 7;
    for (int tp = 0; tp < 16; ++tp) {
        int t = th + tp * 2;
        if (t < NSTEP)
            tile[t][i] = Lall[(long)t * BB * VV + (long)b * VV + v0 + i];
    }
    __syncthreads();
    long obase = (long)b * VV * NSTEP + (long)v0 * NSTEP;
    for (int w = tid; w < 128 * NSTEP; w += 256)
        out[obase + w] = tile[w % NSTEP][w / NSTEP];
}

// ---- detect mask dtype and canonicalize ----
__global__ void mask_canon(const void* __restrict__ maskp, float* __restrict__ mA)
{
    __shared__ int ok;
    const unsigned char* bt = (const unsigned char*)maskp;
    int tid = threadIdx.x;
    if (tid == 0) ok = 1;
    __syncthreads();
    int bad = 0;
    for (int i = tid; i < BB * SS; i += 256) {
        unsigned char v = bt[i];
        if (v > 1) bad = 1;
        if ((i & (SS - 1)) != 0 && bt[i - 1] > v) bad = 1;
    }
    if (bad) atomicAnd(&ok, 0);
    __syncthreads();
    int packed = ok;
    const int* wi = (const int*)maskp;
    for (int i = tid; i < BB * SS; i += 256) {
        int m = packed ? (bt[i] != 0) : (wi[i] != 0);
        mA[i] = m ? -1.0e10f : 0.0f;
    }
}

__global__ void init_state(float* __restrict__ st, int* __restrict__ pred)
{
    int idx = blockIdx.x * 256 + threadIdx.x;
    st[idx] = 0.0f;
    if (idx < BB) pred[idx] = 1;
}

__global__ void sb_kernel(const float* __restrict__ keys, const float* __restrict__ bq,
                          float* __restrict__ sb)
{
    int bs = blockIdx.x * 256 + threadIdx.x;
    const float* kp = keys + (long)bs * DD;
    float a = 0;
    for (int d = 0; d < DD; d += 4) {
        float4 kv = *(const float4*)(kp + d);
        float4 bv = *(const float4*)(bq + d);
        a += kv.x * bv.x + kv.y * bv.y + kv.z * bv.z + kv.w * bv.w;
    }
    sb[bs] = a;
}

extern "C" void kernel_launch(void* const* d_in, const int* in_sizes, int n_in,
                              void* d_out, int out_size, void* d_ws, size_t ws_size,
                              hipStream_t stream)
{
    const float* enc   = (const float*)d_in[0];
    const void*  maskp = d_in[1];
    const float* embt  = (const float*)d_in[2];
    const float* wq    = (const float*)d_in[3];
    const float* bq    = (const float*)d_in[4];
    const float* wk    = (const float*)d_in[5];
    const float* bk    = (const float*)d_in[6];
    const float* w_ih0 = (const float*)d_in[7];
    const float* w_hh0 = (const float*)d_in[8];
    const float* b_ih0 = (const float*)d_in[9];
    const float* b_hh0 = (const float*)d_in[10];
    const float* w_ih1 = (const float*)d_in[11];
    const float* w_hh1 = (const float*)d_in[12];
    const float* b_ih1 = (const float*)d_in[13];
    const float* b_hh1 = (const float*)d_in[14];
    const float* w_out = (const float*)d_in[15];
    const float* b_out = (const float*)d_in[16];

    float* out  = (float*)d_out;
    float* w    = (float*)d_ws;
    float* keys = w + OFF_KEYS;
    float* K2b  = w + OFF_K2;
    float* sbb  = w + OFF_SB;
    float* mA   = w + OFF_MA;
    float* h0   = w + OFF_STATE;
    float* c0   = h0 + BB * HH;
    float* h1   = c0 + BB * HH;
    float* c1   = h1 + BB * HH;
    float* xb   = w + OFF_X;
    float* P    = w + OFF_P;
    int*   pred = (int*)(w + OFF_PRED);
    unsigned short* wh  = (unsigned short*)(w + OFF_WH);
    unsigned short* wl  = (unsigned short*)(w + OFF_WL);
    unsigned short* h1h = (unsigned short*)(w + OFF_H1H);
    unsigned short* h1l = (unsigned short*)(w + OFF_H1L);
    float* wlog = w + OFF_LOG;

    bool can_split = ws_size >= (size_t)TOTAL_FB * 4;
    bool buffered  = ws_size >= (size_t)TOTAL_BUF * 4;

    mask_canon<<<1, 256, 0, stream>>>(maskp, mA);
    init_state<<<512, 256, 0, stream>>>(w + OFF_STATE, pred);

    // keys = enc @ wk^T + bk
    gemm_kernel<1><<<dim3(8, 128), 256, 0, stream>>>(
        enc, wk, bk, keys, BB * SS, DD, DD, (long)DD, 1L, 0L);
    // K2 = keys @ wq
    gemm_kernel<0><<<dim3(4, 128), 256, 0, stream>>>(
        keys, wq, nullptr, K2b, BB * SS, HH, DD, (long)HH, 1L, 0L);
    sb_kernel<<<32, 256, 0, stream>>>(keys, bq, sbb);

    if (can_split)
        split_kernel<<<16000, 256, 0, stream>>>(w_out, wh, wl, VV * HH);

    for (int t = 0; t < NSTEP; ++t) {
        attn_embed<<<BB, 256, 0, stream>>>(h1, K2b, sbb, mA, enc, embt, pred, xb);
        lstm_gates<<<dim3(16, 16), 256, 0, stream>>>(xb, XDIM, w_ih0, h0, HH, w_hh0, 12, P);
        lstm_act<<<128, 256, 0, stream>>>(P, 16, b_ih0, b_hh0, c0, h0, nullptr, nullptr);
        lstm_gates<<<dim3(16, 8), 256, 0, stream>>>(h0, HH, w_ih1, h1, HH, w_hh1, 4, P);
        lstm_act<<<128, 256, 0, stream>>>(P, 8, b_ih1, b_hh1, c1, h1,
                                          can_split ? h1h : nullptr, h1l);

        float* Lt   = buffered ? (wlog + (long)t * BB * VV) : (out + t);
        long   ldm  = buffered ? (long)VV : (long)VV * NSTEP;
        long   ldn  = buffered ? 1L : (long)NSTEP;
        float* Cbase = buffered ? (wlog + (long)t * BB * VV) : out;
        long   coff = buffered ? 0L : (long)t;

        if (can_split) {
            logits_mfma<<<250, 256, 0, stream>>>(h1h, h1l, wh, wl, b_out,
                                                 Cbase, ldm, ldn, coff);
        } else {
            gemm_kernel<1><<<dim3(250, 1), 256, 0, stream>>>(
                h1, w_out, b_out, Cbase, BB, VV, HH, ldm, ldn, coff);
        }
        argmax_kernel<<<BB, 256, 0, stream>>>(Lt, buffered ? (long)VV : (long)VV * NSTEP,
                                              ldn, pred);
    }
    if (buffered)
        transpose_out<<<dim3(BB, VV / 128), 256, 0, stream>>>(wlog, out);
}